// Round 1
// baseline (1337.557 us; speedup 1.0000x reference)
//
#include <hip/hip_runtime.h>
#include <hip/hip_bf16.h>

// MoE Experts: T=8192 tokens, D_MODEL=1024, D_FF=4096, E=8, TOP_K=2, f32 io.
// v1: routing compaction -> bf16 weight convert (ws) -> fused per-expert
// tile GEMM (X stage in LDS, H chunk LDS roundtrip, acc in regs, atomic scatter).

#define T_TOK   8192
#define D_MODEL 1024
#define D_FF    4096
#define NE      8
#define BM      64
#define BF      64
#define NCHUNK  (D_FF / BF)
#define BLOCK   512

typedef float f32x4 __attribute__((ext_vector_type(4)));
typedef short s16x8 __attribute__((ext_vector_type(8)));
typedef unsigned short u16;

__device__ __forceinline__ u16 f2bf(float x) {
  __hip_bfloat16 h = __float2bfloat16(x);   // RNE
  return *reinterpret_cast<u16*>(&h);
}

// ---------------- routing compaction ----------------
__global__ void moe_route(const int* __restrict__ sel, const float* __restrict__ rw,
                          int* __restrict__ cnt, int* __restrict__ tidx,
                          float* __restrict__ tw) {
  int t = blockIdx.x * blockDim.x + threadIdx.x;
  if (t >= T_TOK) return;
  int e0 = 0, e1 = 0;
  #pragma unroll
  for (int e = 0; e < NE; ++e) {
    if (sel[t * 16 + e])     e0 = e;
    if (sel[t * 16 + 8 + e]) e1 = e;
  }
  float w0 = rw[2 * t], w1 = rw[2 * t + 1];
  if (e0 == e1) {
    int p = atomicAdd(&cnt[e0], 1);
    tidx[e0 * T_TOK + p] = t; tw[e0 * T_TOK + p] = w0 + w1;
  } else {
    int p = atomicAdd(&cnt[e0], 1);
    tidx[e0 * T_TOK + p] = t; tw[e0 * T_TOK + p] = w0;
    int q = atomicAdd(&cnt[e1], 1);
    tidx[e1 * T_TOK + q] = t; tw[e1 * T_TOK + q] = w1;
  }
}

// ---------------- f32 -> bf16 weight convert ----------------
__global__ void moe_cvt_w(const float* __restrict__ wi, const float* __restrict__ wo,
                          u16* __restrict__ wib, u16* __restrict__ wob) {
  const size_t NW = (size_t)NE * D_FF * D_MODEL;   // 33554432
  size_t i = ((size_t)blockIdx.x * blockDim.x + threadIdx.x) * 8;
  const float* src; u16* dst;
  if (i < NW) { src = wi + i; dst = wib + i; }
  else        { src = wo + (i - NW); dst = wob + (i - NW); }
  float4 a = *(const float4*)(src);
  float4 b = *(const float4*)(src + 4);
  s16x8 v;
  v[0] = (short)f2bf(a.x); v[1] = (short)f2bf(a.y);
  v[2] = (short)f2bf(a.z); v[3] = (short)f2bf(a.w);
  v[4] = (short)f2bf(b.x); v[5] = (short)f2bf(b.y);
  v[6] = (short)f2bf(b.z); v[7] = (short)f2bf(b.w);
  *(s16x8*)dst = v;
}

// ---------------- weight fragment loader ----------------
template <bool PRE>
__device__ __forceinline__ s16x8 load_w(const u16* __restrict__ wb,
                                        const float* __restrict__ wf, size_t off) {
  if constexpr (PRE) {
    return *(const s16x8*)(wb + off);
  } else {
    float4 a = *(const float4*)(wf + off);
    float4 b = *(const float4*)(wf + off + 4);
    s16x8 v;
    v[0] = (short)f2bf(a.x); v[1] = (short)f2bf(a.y);
    v[2] = (short)f2bf(a.z); v[3] = (short)f2bf(a.w);
    v[4] = (short)f2bf(b.x); v[5] = (short)f2bf(b.y);
    v[6] = (short)f2bf(b.z); v[7] = (short)f2bf(b.w);
    return v;
  }
}

// ---------------- fused expert MLP ----------------
// grid: 1024 blocks (1D). e = bid&7 (XCD phase-lock), tile = bid>>3.
// 8 waves. GEMM1: wave -> (mt1 = w&3 [16 rows], fpair = w>>2 [32 ff cols]).
// GEMM2: wave -> [64 rows x 128 cols], nq = w. acc2[4][8] f32x4.
template <bool PRE>
__global__ __launch_bounds__(BLOCK, 2)
void moe_fused(const float* __restrict__ hs,
               const u16* __restrict__ wib, const u16* __restrict__ wob,
               const float* __restrict__ wif, const float* __restrict__ wof,
               const int* __restrict__ tidx, const float* __restrict__ tw,
               const int* __restrict__ cnt, float* __restrict__ out) {
  int b = blockIdx.x;
  int e = b & 7;
  int tile = b >> 3;
  int n_e = cnt[e];
  int base = tile * BM;
  if (base >= n_e) return;
  int rows = min(BM, n_e - base);

  extern __shared__ char smem[];
  char* Xs = smem;                        // bf16 [64][1024] swizzled: 131072 B
  char* Hs = smem + 131072;               // bf16 [64][64]  swizzled: 8192 B
  int*   s_tok = (int*)(smem + 139264);   // 64 ints
  float* s_w   = (float*)(smem + 139520); // 64 floats

  int tid = threadIdx.x;
  int lane = tid & 63;
  int wv = tid >> 6;
  int lg = lane >> 4;   // 0..3
  int ll = lane & 15;   // 0..15

  if (tid < BM) {
    int ok = tid < rows;
    s_tok[tid] = ok ? tidx[e * T_TOK + base + tid] : 0;
    s_w[tid]   = ok ? tw[e * T_TOK + base + tid] : 0.0f;
  }
  __syncthreads();

  // ---- stage X tile (gather + f32->bf16), XOR swizzle bits 4..6 per row ----
  {
    int row = tid >> 3;
    int seg = tid & 7;
    const float* src = hs + (size_t)s_tok[row] * D_MODEL + seg * 128;
    char* drow = Xs + row * 2048;
    int swz = (row & 7) << 4;
    #pragma unroll
    for (int c = 0; c < 16; ++c) {
      float4 f0 = *(const float4*)(src + c * 8);
      float4 f1 = *(const float4*)(src + c * 8 + 4);
      s16x8 v;
      v[0] = (short)f2bf(f0.x); v[1] = (short)f2bf(f0.y);
      v[2] = (short)f2bf(f0.z); v[3] = (short)f2bf(f0.w);
      v[4] = (short)f2bf(f1.x); v[5] = (short)f2bf(f1.y);
      v[6] = (short)f2bf(f1.z); v[7] = (short)f2bf(f1.w);
      int byte = (seg * 256 + c * 16) ^ swz;
      *(s16x8*)(drow + byte) = v;
    }
  }
  __syncthreads();

  f32x4 acc2[4][8];
  #pragma unroll
  for (int mt = 0; mt < 4; ++mt)
    #pragma unroll
    for (int nt = 0; nt < 8; ++nt)
      acc2[mt][nt] = (f32x4){0.f, 0.f, 0.f, 0.f};

  const int mt1 = wv & 3;     // GEMM1 m-tile
  const int fp  = wv >> 2;    // GEMM1 ff-pair (32 cols)
  const int xrow1 = mt1 * 16 + ll;
  const char* xbase = Xs + xrow1 * 2048;
  const int xswz = (xrow1 & 7) << 4;

  for (int ffc = 0; ffc < NCHUNK; ++ffc) {
    // ---- GEMM1: H[64,64] = relu(X[64,1024] @ Wi_chunk^T) ----
    f32x4 acc1[2] = {{0.f,0.f,0.f,0.f},{0.f,0.f,0.f,0.f}};
    size_t wr0 = ((size_t)e * D_FF + (size_t)ffc * 64 + fp * 32 + ll) * D_MODEL + lg * 8;
    size_t wr1 = wr0 + (size_t)16 * D_MODEL;
    #pragma unroll
    for (int kk = 0; kk < 32; ++kk) {
      s16x8 a  = *(const s16x8*)(xbase + ((kk * 64 + lg * 16) ^ xswz));
      s16x8 b0 = load_w<PRE>(wib, wif, wr0 + kk * 32);
      s16x8 b1 = load_w<PRE>(wib, wif, wr1 + kk * 32);
      acc1[0] = __builtin_amdgcn_mfma_f32_16x16x32_bf16(a, b0, acc1[0], 0, 0, 0);
      acc1[1] = __builtin_amdgcn_mfma_f32_16x16x32_bf16(a, b1, acc1[1], 0, 0, 0);
    }
    __syncthreads();   // previous GEMM2 done reading Hs
    #pragma unroll
    for (int fi = 0; fi < 2; ++fi) {
      int f = fp * 32 + fi * 16 + ll;
      #pragma unroll
      for (int r = 0; r < 4; ++r) {
        int m = mt1 * 16 + lg * 4 + r;
        float v = acc1[fi][r];
        v = v > 0.f ? v : 0.f;              // relu
        *(u16*)(Hs + m * 128 + ((f * 2) ^ ((m & 7) << 4))) = f2bf(v);
      }
    }
    __syncthreads();   // Hs ready

    // ---- GEMM2: Y[64,1024] += H[64,64] @ Wo_chunk^T ----
    #pragma unroll
    for (int kk = 0; kk < 2; ++kk) {
      s16x8 a[4];
      #pragma unroll
      for (int mt = 0; mt < 4; ++mt) {
        int m = mt * 16 + ll;
        a[mt] = *(const s16x8*)(Hs + m * 128 + ((kk * 64 + lg * 16) ^ ((m & 7) << 4)));
      }
      #pragma unroll
      for (int nt = 0; nt < 8; ++nt) {
        size_t nrow = (size_t)e * D_MODEL + wv * 128 + nt * 16 + ll;
        s16x8 bf = load_w<PRE>(wob, wof, nrow * D_FF + (size_t)ffc * 64 + kk * 32 + lg * 8);
        #pragma unroll
        for (int mt = 0; mt < 4; ++mt)
          acc2[mt][nt] = __builtin_amdgcn_mfma_f32_16x16x32_bf16(a[mt], bf, acc2[mt][nt], 0, 0, 0);
      }
    }
  }

  // ---- epilogue: weighted atomic scatter (<=2 adders per output element) ----
  #pragma unroll
  for (int mt = 0; mt < 4; ++mt) {
    #pragma unroll
    for (int r = 0; r < 4; ++r) {
      int m = mt * 16 + lg * 4 + r;
      if (m < rows) {
        float w = s_w[m];
        float* orow = out + (size_t)s_tok[m] * D_MODEL + wv * 128 + ll;
        #pragma unroll
        for (int nt = 0; nt < 8; ++nt)
          atomicAdd(orow + nt * 16, acc2[mt][nt][r] * w);
      }
    }
  }
}

// ---------------- host ----------------
extern "C" void kernel_launch(void* const* d_in, const int* in_sizes, int n_in,
                              void* d_out, int out_size, void* d_ws, size_t ws_size,
                              hipStream_t stream) {
  const float* hs  = (const float*)d_in[0];
  const int*   sel = (const int*)d_in[1];
  const float* rw  = (const float*)d_in[2];
  const float* wi  = (const float*)d_in[3];
  const float* wo  = (const float*)d_in[4];
  float* out = (float*)d_out;

  const size_t NW = (size_t)NE * D_FF * D_MODEL;          // 33,554,432 per array
  const size_t pre_bytes  = 2 * NW * sizeof(u16);          // 128 MiB
  const size_t list_elems = (size_t)NE * T_TOK;
  const size_t list_bytes = list_elems * (sizeof(int) + sizeof(float)) + 64;
  const bool pre = ws_size >= pre_bytes + list_bytes;

  char* ws = (char*)d_ws;
  u16 *wib = nullptr, *wob = nullptr;
  int* tidx;
  if (pre) {
    wib = (u16*)ws;
    wob = wib + NW;
    tidx = (int*)(ws + pre_bytes);
  } else {
    tidx = (int*)ws;
  }
  float* tw  = (float*)(tidx + list_elems);
  int*   cnt = (int*)(tw + list_elems);

  hipMemsetAsync(d_out, 0, (size_t)T_TOK * D_MODEL * sizeof(float), stream);
  hipMemsetAsync(cnt, 0, NE * sizeof(int), stream);
  moe_route<<<T_TOK / 256, 256, 0, stream>>>(sel, rw, cnt, tidx, tw);

  const size_t SMEM = 139776;
  if (pre) {
    moe_cvt_w<<<(int)((2 * NW / 8) / 256), 256, 0, stream>>>(wi, wo, wib, wob);
    hipFuncSetAttribute(reinterpret_cast<const void*>(&moe_fused<true>),
                        hipFuncAttributeMaxDynamicSharedMemorySize, (int)SMEM);
    moe_fused<true><<<NE * (T_TOK / BM), BLOCK, SMEM, stream>>>(
        hs, wib, wob, nullptr, nullptr, tidx, tw, cnt, out);
  } else {
    hipFuncSetAttribute(reinterpret_cast<const void*>(&moe_fused<false>),
                        hipFuncAttributeMaxDynamicSharedMemorySize, (int)SMEM);
    moe_fused<false><<<NE * (T_TOK / BM), BLOCK, SMEM, stream>>>(
        hs, nullptr, nullptr, wi, wo, tidx, tw, cnt, out);
  }
}

// Round 2
// 785.429 us; speedup vs baseline: 1.7030x; 1.7030x over previous
//
#include <hip/hip_runtime.h>
#include <hip/hip_bf16.h>

// MoE Experts v2: two-pass grouped GEMM (m97 structure: 128x128 tile, BK=64,
// 2 barriers/K-step, global_load_lds for bf16 operands, 4 waves/block).
// route -> tilemap (128-aligned per-expert segments) -> [cvt weights bf16]
// -> GEMM1 (H = relu(Xg @ Wi^T)) -> GEMM2 (out += w * H @ Wo^T, atomic scatter).

#define T_TOK   8192
#define D_MODEL 1024
#define D_FF    4096
#define NE      8
#define BM      128
#define BK      64
#define MT_MAX  136                 // max 128-row tiles after per-expert padding
#define ROWS_MAX (MT_MAX * 128)

typedef float f32x4 __attribute__((ext_vector_type(4)));
typedef short s16x8 __attribute__((ext_vector_type(8)));
typedef unsigned short u16;

__device__ __forceinline__ u16 f2bf(float x) {
  __hip_bfloat16 h = __float2bfloat16(x);   // RNE
  return *reinterpret_cast<u16*>(&h);
}

__device__ __forceinline__ s16x8 cvt8(float4 a, float4 b) {
  s16x8 v;
  v[0] = (short)f2bf(a.x); v[1] = (short)f2bf(a.y);
  v[2] = (short)f2bf(a.z); v[3] = (short)f2bf(a.w);
  v[4] = (short)f2bf(b.x); v[5] = (short)f2bf(b.y);
  v[6] = (short)f2bf(b.z); v[7] = (short)f2bf(b.w);
  return v;
}

// async global->LDS, 16B per lane; LDS dest must be linear base + lane*16
__device__ __forceinline__ void gload_lds16(const void* g, void* l) {
  __builtin_amdgcn_global_load_lds((const __attribute__((address_space(1))) void*)g,
                                   (__attribute__((address_space(3))) void*)l,
                                   16, 0, 0);
}

// ---------------- routing compaction ----------------
__global__ void moe_route(const int* __restrict__ sel, const float* __restrict__ rw,
                          int* __restrict__ cnt, int* __restrict__ tidx,
                          float* __restrict__ tw) {
  int t = blockIdx.x * blockDim.x + threadIdx.x;
  if (t >= T_TOK) return;
  int e0 = 0, e1 = 0;
  #pragma unroll
  for (int e = 0; e < NE; ++e) {
    if (sel[t * 16 + e])     e0 = e;
    if (sel[t * 16 + 8 + e]) e1 = e;
  }
  float w0 = rw[2 * t], w1 = rw[2 * t + 1];
  if (e0 == e1) {
    int p = atomicAdd(&cnt[e0], 1);
    tidx[e0 * T_TOK + p] = t; tw[e0 * T_TOK + p] = w0 + w1;
  } else {
    int p = atomicAdd(&cnt[e0], 1);
    tidx[e0 * T_TOK + p] = t; tw[e0 * T_TOK + p] = w0;
    int q = atomicAdd(&cnt[e1], 1);
    tidx[e1 * T_TOK + q] = t; tw[e1 * T_TOK + q] = w1;
  }
}

// ---------------- tile map: 128-aligned per-expert segments ----------------
__global__ void moe_tilemap(const int* __restrict__ cnt, const int* __restrict__ tidx,
                            const float* __restrict__ tw, int* __restrict__ tile_e,
                            int* __restrict__ tokr, float* __restrict__ wr) {
  __shared__ int off[NE + 1];
  int tid = threadIdx.x;
  if (tid == 0) {
    int o = 0;
    for (int e = 0; e < NE; ++e) { off[e] = o; o += (cnt[e] + 127) & ~127; }
    off[NE] = o;
  }
  __syncthreads();
  int total = off[NE];
  for (int t = tid; t < MT_MAX; t += blockDim.x) {
    int r0 = t * 128;
    int e = -1;
    if (r0 < total) {
      for (int i = NE - 1; i >= 0; --i) if (r0 >= off[i]) { e = i; break; }
    }
    tile_e[t] = e;
  }
  for (int e = 0; e < NE; ++e) {
    int n = cnt[e], p = (n + 127) & ~127, o = off[e];
    for (int i = tid; i < p; i += blockDim.x) {
      tokr[o + i] = (i < n) ? tidx[e * T_TOK + i] : -1;
      wr[o + i]   = (i < n) ? tw[e * T_TOK + i] : 0.f;
    }
  }
}

// ---------------- f32 -> bf16 weight convert ----------------
__global__ void moe_cvt_w(const float* __restrict__ wi, const float* __restrict__ wo,
                          u16* __restrict__ wib, u16* __restrict__ wob) {
  const size_t NW = (size_t)NE * D_FF * D_MODEL;
  size_t i = ((size_t)blockIdx.x * blockDim.x + threadIdx.x) * 8;
  const float* src; u16* dst;
  if (i < NW) { src = wi + i; dst = wib + i; }
  else        { src = wo + (i - NW); dst = wob + (i - NW); }
  float4 a = *(const float4*)(src);
  float4 b = *(const float4*)(src + 4);
  *(s16x8*)dst = cvt8(a, b);
}

// ---------------- GEMM1: H[row, W] = relu(Xg @ Wi^T) chunk ----------------
// grid (MT_MAX, W/128), 256 thr (4 waves 2x2), each wave 64x64 out.
template <bool PRE>
__global__ __launch_bounds__(256, 3)
void moe_gemm1(const float* __restrict__ hs,
               const u16* __restrict__ wib, const float* __restrict__ wif,
               const int* __restrict__ tile_e, const int* __restrict__ tokr,
               u16* __restrict__ H, int W, int f0) {
  __shared__ u16 As[BM * BK];
  __shared__ u16 Bs[BM * BK];
  __shared__ int s_tok[BM];

  const int mt = blockIdx.x;
  const int e = tile_e[mt];
  if (e < 0) return;
  const int grow0 = mt * 128;
  const int fcol0 = f0 + blockIdx.y * 128;

  const int tid = threadIdx.x;
  const int lane = tid & 63, wv = tid >> 6;
  const int lg = lane >> 4, ll = lane & 15;
  const int wm = wv >> 1, wn = wv & 1;

  if (tid < BM) { int tk = tokr[grow0 + tid]; s_tok[tid] = tk < 0 ? 0 : tk; }
  __syncthreads();

  const int ar = tid >> 1, ac = (tid & 1) * 32;
  const float* asrc = hs + (size_t)s_tok[ar] * D_MODEL + ac;
  u16* adst = As + ar * BK + ac;

  const u16*   bsrcb = wib + ((size_t)e * D_FF + fcol0) * D_MODEL;
  const float* bsrcf = wif ? wif + ((size_t)e * D_FF + fcol0) * D_MODEL : nullptr;
  const int br = tid >> 1, bc = (tid & 1) * 32;

  f32x4 acc[4][4];
  #pragma unroll
  for (int m = 0; m < 4; ++m)
    #pragma unroll
    for (int n = 0; n < 4; ++n) acc[m][n] = (f32x4){0.f, 0.f, 0.f, 0.f};

  for (int kk = 0; kk < D_MODEL / BK; ++kk) {
    __syncthreads();
    // A: gathered f32 rows -> bf16 LDS (reg-staged)
    {
      const float* p = asrc + kk * BK;
      #pragma unroll
      for (int i = 0; i < 4; ++i) {
        float4 x0 = *(const float4*)(p + i * 8);
        float4 x1 = *(const float4*)(p + i * 8 + 4);
        *(s16x8*)(adst + i * 8) = cvt8(x0, x1);
      }
    }
    // B: Wi chunk
    if constexpr (PRE) {
      #pragma unroll
      for (int i = 0; i < 4; ++i) {
        int off = wv * 4096 + i * 1024 + lane * 16;  // linear LDS bytes
        int row = off >> 7, colb = off & 127;
        gload_lds16(bsrcb + (size_t)row * D_MODEL + kk * BK + (colb >> 1),
                    (char*)Bs + off);
      }
    } else {
      const float* q = bsrcf + (size_t)br * D_MODEL + kk * BK + bc;
      u16* bdst = Bs + br * BK + bc;
      #pragma unroll
      for (int i = 0; i < 4; ++i) {
        float4 x0 = *(const float4*)(q + i * 8);
        float4 x1 = *(const float4*)(q + i * 8 + 4);
        *(s16x8*)(bdst + i * 8) = cvt8(x0, x1);
      }
    }
    __syncthreads();
    #pragma unroll
    for (int kb = 0; kb < 2; ++kb) {
      s16x8 af[4], bf[4];
      #pragma unroll
      for (int m = 0; m < 4; ++m)
        af[m] = *(const s16x8*)(As + (wm * 64 + m * 16 + ll) * BK + kb * 32 + lg * 8);
      #pragma unroll
      for (int n = 0; n < 4; ++n)
        bf[n] = *(const s16x8*)(Bs + (wn * 64 + n * 16 + ll) * BK + kb * 32 + lg * 8);
      #pragma unroll
      for (int m = 0; m < 4; ++m)
        #pragma unroll
        for (int n = 0; n < 4; ++n)
          acc[m][n] = __builtin_amdgcn_mfma_f32_16x16x32_bf16(af[m], bf[n], acc[m][n], 0, 0, 0);
    }
  }

  const int hc0 = fcol0 - f0;   // pass-local H column base
  #pragma unroll
  for (int m = 0; m < 4; ++m) {
    #pragma unroll
    for (int r = 0; r < 4; ++r) {
      int row = wm * 64 + m * 16 + lg * 4 + r;
      u16* hp = H + (size_t)(grow0 + row) * W + hc0 + wn * 64 + ll;
      #pragma unroll
      for (int n = 0; n < 4; ++n) {
        float v = acc[m][n][r];
        hp[n * 16] = f2bf(v > 0.f ? v : 0.f);
      }
    }
  }
}

// ---------------- GEMM2: out += w .* (H @ Wo^T chunk) ----------------
template <bool PRE>
__global__ __launch_bounds__(256, 3)
void moe_gemm2(const u16* __restrict__ H,
               const u16* __restrict__ wob, const float* __restrict__ wof,
               const int* __restrict__ tile_e, const int* __restrict__ tokr,
               const float* __restrict__ wr, float* __restrict__ out,
               int W, int f0) {
  __shared__ u16 As[BM * BK];
  __shared__ u16 Bs[BM * BK];
  __shared__ int s_tok[BM];
  __shared__ float s_w[BM];

  const int mt = blockIdx.x;
  const int e = tile_e[mt];
  if (e < 0) return;
  const int grow0 = mt * 128;
  const int dcol0 = blockIdx.y * 128;

  const int tid = threadIdx.x;
  const int lane = tid & 63, wv = tid >> 6;
  const int lg = lane >> 4, ll = lane & 15;
  const int wm = wv >> 1, wn = wv & 1;

  if (tid < BM) { s_tok[tid] = tokr[grow0 + tid]; s_w[tid] = wr[grow0 + tid]; }
  __syncthreads();

  const u16* abase = H + (size_t)grow0 * W;
  const u16*   bsrcb = wob + ((size_t)e * D_MODEL + dcol0) * D_FF;
  const float* bsrcf = wof ? wof + ((size_t)e * D_MODEL + dcol0) * D_FF : nullptr;
  const int br = tid >> 1, bc = (tid & 1) * 32;

  f32x4 acc[4][4];
  #pragma unroll
  for (int m = 0; m < 4; ++m)
    #pragma unroll
    for (int n = 0; n < 4; ++n) acc[m][n] = (f32x4){0.f, 0.f, 0.f, 0.f};

  for (int kk = 0; kk < W / BK; ++kk) {
    __syncthreads();
    // A: H rows (bf16, pitch W) via global_load_lds
    #pragma unroll
    for (int i = 0; i < 4; ++i) {
      int off = wv * 4096 + i * 1024 + lane * 16;
      int row = off >> 7, colb = off & 127;
      gload_lds16(abase + (size_t)row * W + kk * BK + (colb >> 1), (char*)As + off);
    }
    // B: Wo chunk
    if constexpr (PRE) {
      #pragma unroll
      for (int i = 0; i < 4; ++i) {
        int off = wv * 4096 + i * 1024 + lane * 16;
        int row = off >> 7, colb = off & 127;
        gload_lds16(bsrcb + (size_t)row * D_FF + f0 + kk * BK + (colb >> 1),
                    (char*)Bs + off);
      }
    } else {
      const float* q = bsrcf + (size_t)br * D_FF + f0 + kk * BK + bc;
      u16* bdst = Bs + br * BK + bc;
      #pragma unroll
      for (int i = 0; i < 4; ++i) {
        float4 x0 = *(const float4*)(q + i * 8);
        float4 x1 = *(const float4*)(q + i * 8 + 4);
        *(s16x8*)(bdst + i * 8) = cvt8(x0, x1);
      }
    }
    __syncthreads();
    #pragma unroll
    for (int kb = 0; kb < 2; ++kb) {
      s16x8 af[4], bf[4];
      #pragma unroll
      for (int m = 0; m < 4; ++m)
        af[m] = *(const s16x8*)(As + (wm * 64 + m * 16 + ll) * BK + kb * 32 + lg * 8);
      #pragma unroll
      for (int n = 0; n < 4; ++n)
        bf[n] = *(const s16x8*)(Bs + (wn * 64 + n * 16 + ll) * BK + kb * 32 + lg * 8);
      #pragma unroll
      for (int m = 0; m < 4; ++m)
        #pragma unroll
        for (int n = 0; n < 4; ++n)
          acc[m][n] = __builtin_amdgcn_mfma_f32_16x16x32_bf16(af[m], bf[n], acc[m][n], 0, 0, 0);
    }
  }

  #pragma unroll
  for (int m = 0; m < 4; ++m) {
    #pragma unroll
    for (int r = 0; r < 4; ++r) {
      int row = wm * 64 + m * 16 + lg * 4 + r;
      int tok = s_tok[row];
      float w = s_w[row];
      if (tok >= 0) {
        float* op = out + (size_t)tok * D_MODEL + dcol0 + wn * 64 + ll;
        #pragma unroll
        for (int n = 0; n < 4; ++n)
          atomicAdd(op + n * 16, acc[m][n][r] * w);
      }
    }
  }
}

// ---------------- host ----------------
extern "C" void kernel_launch(void* const* d_in, const int* in_sizes, int n_in,
                              void* d_out, int out_size, void* d_ws, size_t ws_size,
                              hipStream_t stream) {
  const float* hs  = (const float*)d_in[0];
  const int*   sel = (const int*)d_in[1];
  const float* rw  = (const float*)d_in[2];
  const float* wi  = (const float*)d_in[3];
  const float* wo  = (const float*)d_in[4];
  float* out = (float*)d_out;

  const size_t NW = (size_t)NE * D_FF * D_MODEL;
  const size_t wb_bytes = 2 * NW * sizeof(u16);                  // 128 MiB

  const size_t tidx_b = (size_t)NE * T_TOK * 4;
  const size_t tw_b   = (size_t)NE * T_TOK * 4;
  const size_t tokr_b = (size_t)ROWS_MAX * 4;
  const size_t wr_b   = (size_t)ROWS_MAX * 4;
  const size_t te_b   = (size_t)MT_MAX * 4;
  const size_t cnt_b  = 256;
  const size_t ctrl   = (tidx_b + tw_b + tokr_b + wr_b + te_b + cnt_b + 4095) & ~4095UL;

  // pick smallest ff-split FS; prefer pre-converted bf16 weights at equal FS
  bool pre = false; int FS = 32; bool picked = false;
  for (int f : {1, 2, 4, 8, 16, 32}) {
    size_t hb = (size_t)ROWS_MAX * (D_FF / f) * 2;
    if (ctrl + wb_bytes + hb <= ws_size) { pre = true;  FS = f; picked = true; break; }
    if (ctrl + hb <= ws_size)            { pre = false; FS = f; picked = true; break; }
  }
  (void)picked;

  char* ws = (char*)d_ws;
  u16* wib = (u16*)ws;
  u16* wob = wib + NW;
  char* cb = ws + (pre ? wb_bytes : 0);
  int*   tidx = (int*)cb;
  float* tw   = (float*)(cb + tidx_b);
  int*   tokr = (int*)(cb + tidx_b + tw_b);
  float* wrr  = (float*)(cb + tidx_b + tw_b + tokr_b);
  int*   te   = (int*)(cb + tidx_b + tw_b + tokr_b + wr_b);
  int*   cnt  = (int*)(cb + tidx_b + tw_b + tokr_b + wr_b + te_b);
  u16*   Hbuf = (u16*)(cb + ctrl);

  hipMemsetAsync(d_out, 0, (size_t)out_size * sizeof(float), stream);
  hipMemsetAsync(cnt, 0, NE * sizeof(int), stream);
  moe_route<<<T_TOK / 256, 256, 0, stream>>>(sel, rw, cnt, tidx, tw);
  moe_tilemap<<<1, 256, 0, stream>>>(cnt, tidx, tw, te, tokr, wrr);
  if (pre)
    moe_cvt_w<<<(int)(2 * NW / 8 / 256), 256, 0, stream>>>(wi, wo, wib, wob);

  const int W = D_FF / FS;
  for (int p = 0; p < FS; ++p) {
    const int f0 = p * W;
    if (pre) {
      moe_gemm1<true><<<dim3(MT_MAX, W / 128), 256, 0, stream>>>(
          hs, wib, nullptr, te, tokr, Hbuf, W, f0);
      moe_gemm2<true><<<dim3(MT_MAX, 8), 256, 0, stream>>>(
          Hbuf, wob, nullptr, te, tokr, wrr, out, W, f0);
    } else {
      moe_gemm1<false><<<dim3(MT_MAX, W / 128), 256, 0, stream>>>(
          hs, nullptr, wi, te, tokr, Hbuf, W, f0);
      moe_gemm2<false><<<dim3(MT_MAX, 8), 256, 0, stream>>>(
          Hbuf, nullptr, wo, te, tokr, wrr, out, W, f0);
    }
  }
}

// Round 3
// 623.829 us; speedup vs baseline: 2.1441x; 1.2590x over previous
//
#include <hip/hip_runtime.h>
#include <hip/hip_bf16.h>

// MoE Experts v3: two-pass grouped GEMM, all-bf16 hot loops.
// route -> tilemap(+pos) -> [gather Xg bf16] -> [cvt weights bf16]
// -> GEMM1 (H = relu(Xg @ Wi^T), gload_lds both operands)
// -> GEMM2 (Y += w * H @ Wo^T, exclusive-ownership f32 buffer)
// -> combine (out[t] = Y[pos0] + Y[pos1]).
// ws-adaptive: PRE (bf16 weights), YB (Y buffer vs atomics), XG (pre-gathered
// bf16 X vs in-kernel f32 gather), FS (ff split for H buffer).

#define T_TOK   8192
#define D_MODEL 1024
#define D_FF    4096
#define NE      8
#define BM      128
#define BK      64
#define MT_MAX  136
#define ROWS_MAX (MT_MAX * 128)

typedef float f32x4 __attribute__((ext_vector_type(4)));
typedef short s16x8 __attribute__((ext_vector_type(8)));
typedef short s16x4 __attribute__((ext_vector_type(4)));
typedef unsigned short u16;

__device__ __forceinline__ u16 f2bf(float x) {
  __hip_bfloat16 h = __float2bfloat16(x);   // RNE
  return *reinterpret_cast<u16*>(&h);
}

__device__ __forceinline__ s16x8 cvt8(float4 a, float4 b) {
  s16x8 v;
  v[0] = (short)f2bf(a.x); v[1] = (short)f2bf(a.y);
  v[2] = (short)f2bf(a.z); v[3] = (short)f2bf(a.w);
  v[4] = (short)f2bf(b.x); v[5] = (short)f2bf(b.y);
  v[6] = (short)f2bf(b.z); v[7] = (short)f2bf(b.w);
  return v;
}

__device__ __forceinline__ void gload_lds16(const void* g, void* l) {
  __builtin_amdgcn_global_load_lds((const __attribute__((address_space(1))) void*)g,
                                   (__attribute__((address_space(3))) void*)l,
                                   16, 0, 0);
}

// ---------------- routing compaction ----------------
__global__ void moe_route(const int* __restrict__ sel, const float* __restrict__ rw,
                          int* __restrict__ cnt, int* __restrict__ tidx,
                          float* __restrict__ tw) {
  int t = blockIdx.x * blockDim.x + threadIdx.x;
  if (t >= T_TOK) return;
  int e0 = 0, e1 = 0;
  #pragma unroll
  for (int e = 0; e < NE; ++e) {
    if (sel[t * 16 + e])     e0 = e;
    if (sel[t * 16 + 8 + e]) e1 = e;
  }
  float w0 = rw[2 * t], w1 = rw[2 * t + 1];
  if (e0 == e1) {
    int p = atomicAdd(&cnt[e0], 1);
    tidx[e0 * T_TOK + p] = t; tw[e0 * T_TOK + p] = w0 + w1;
  } else {
    int p = atomicAdd(&cnt[e0], 1);
    tidx[e0 * T_TOK + p] = t; tw[e0 * T_TOK + p] = w0;
    int q = atomicAdd(&cnt[e1], 1);
    tidx[e1 * T_TOK + q] = t; tw[e1 * T_TOK + q] = w1;
  }
}

// ---------------- tile map + inverse positions ----------------
__global__ void moe_tilemap(const int* __restrict__ cnt, const int* __restrict__ tidx,
                            const float* __restrict__ tw, int* __restrict__ tile_e,
                            int* __restrict__ tokr, float* __restrict__ wr,
                            int* __restrict__ pos, int* __restrict__ pcnt) {
  __shared__ int off[NE + 1];
  int tid = threadIdx.x;
  if (tid == 0) {
    int o = 0;
    for (int e = 0; e < NE; ++e) { off[e] = o; o += (cnt[e] + 127) & ~127; }
    off[NE] = o;
  }
  __syncthreads();
  int total = off[NE];
  for (int t = tid; t < MT_MAX; t += blockDim.x) {
    int r0 = t * 128;
    int e = -1;
    if (r0 < total) {
      for (int i = NE - 1; i >= 0; --i) if (r0 >= off[i]) { e = i; break; }
    }
    tile_e[t] = e;
  }
  for (int e = 0; e < NE; ++e) {
    int n = cnt[e], p = (n + 127) & ~127, o = off[e];
    for (int i = tid; i < p; i += blockDim.x) {
      if (i < n) {
        int t = tidx[e * T_TOK + i];
        tokr[o + i] = t; wr[o + i] = tw[e * T_TOK + i];
        int slot = atomicAdd(&pcnt[t], 1);
        pos[2 * t + slot] = o + i;
      } else {
        tokr[o + i] = -1; wr[o + i] = 0.f;
      }
    }
  }
}

// ---------------- gather X rows -> bf16 Xg ----------------
__global__ void moe_gather_x(const float* __restrict__ hs, const int* __restrict__ tokr,
                             u16* __restrict__ Xg) {
  int row = blockIdx.x;
  int tok = tokr[row];
  int c = threadIdx.x * 4;
  u16* dst = Xg + (size_t)row * D_MODEL + c;
  s16x4 o;
  if (tok < 0) {
    o[0] = o[1] = o[2] = o[3] = 0;
  } else {
    float4 v = *(const float4*)(hs + (size_t)tok * D_MODEL + c);
    o[0] = (short)f2bf(v.x); o[1] = (short)f2bf(v.y);
    o[2] = (short)f2bf(v.z); o[3] = (short)f2bf(v.w);
  }
  *(s16x4*)dst = o;
}

// ---------------- f32 -> bf16 weight convert ----------------
__global__ void moe_cvt_w(const float* __restrict__ wi, const float* __restrict__ wo,
                          u16* __restrict__ wib, u16* __restrict__ wob) {
  const size_t NW = (size_t)NE * D_FF * D_MODEL;
  size_t i = ((size_t)blockIdx.x * blockDim.x + threadIdx.x) * 8;
  const float* src; u16* dst;
  if (i < NW) { src = wi + i; dst = wib + i; }
  else        { src = wo + (i - NW); dst = wob + (i - NW); }
  float4 a = *(const float4*)(src);
  float4 b = *(const float4*)(src + 4);
  *(s16x8*)dst = cvt8(a, b);
}

// ---------------- GEMM1: H[row, 0..W) = relu(Xg @ Wi^T chunk) ----------------
// grid: MT_MAX * (W/128) flattened, XCD-chunked swizzle. 4 waves, 64x64/wave.
template <bool PRE, bool XG>
__global__ __launch_bounds__(256, 3)
void moe_gemm1(const float* __restrict__ hs, const u16* __restrict__ Xg,
               const u16* __restrict__ wib, const float* __restrict__ wif,
               const int* __restrict__ tile_e, const int* __restrict__ tokr,
               u16* __restrict__ H, int W, int f0) {
  __shared__ u16 As[BM * BK];
  __shared__ u16 Bs[BM * BK];
  __shared__ int s_tok[BM];

  const int nwg = gridDim.x;
  const int bid = blockIdx.x;
  const int wg = (bid & 7) * (nwg >> 3) + (bid >> 3);   // nwg % 8 == 0
  const int mt = wg % MT_MAX;
  const int yb = wg / MT_MAX;

  const int e = tile_e[mt];
  if (e < 0) return;
  const int grow0 = mt * 128;
  const int fcol0 = f0 + yb * 128;

  const int tid = threadIdx.x;
  const int lane = tid & 63, wv = tid >> 6;
  const int lg = lane >> 4, ll = lane & 15;
  const int wm = wv >> 1, wn = wv & 1;

  if constexpr (!XG) {
    if (tid < BM) { int tk = tokr[grow0 + tid]; s_tok[tid] = tk < 0 ? 0 : tk; }
    __syncthreads();
  }

  const int ar = tid >> 1, ac = (tid & 1) * 32;
  const float* asrc = XG ? nullptr : hs + (size_t)s_tok[ar] * D_MODEL + ac;
  u16* adst = As + ar * BK + ac;

  const u16*   bsrcb = PRE ? wib + ((size_t)e * D_FF + fcol0) * D_MODEL : nullptr;
  const float* bsrcf = PRE ? nullptr : wif + ((size_t)e * D_FF + fcol0) * D_MODEL;
  const int br = tid >> 1, bc = (tid & 1) * 32;

  f32x4 acc[4][4];
  #pragma unroll
  for (int m = 0; m < 4; ++m)
    #pragma unroll
    for (int n = 0; n < 4; ++n) acc[m][n] = (f32x4){0.f, 0.f, 0.f, 0.f};

  for (int kk = 0; kk < D_MODEL / BK; ++kk) {
    __syncthreads();
    if constexpr (XG) {
      const u16* abase = Xg + (size_t)grow0 * D_MODEL + kk * BK;
      #pragma unroll
      for (int i = 0; i < 4; ++i) {
        int off = wv * 4096 + i * 1024 + lane * 16;
        int row = off >> 7, colb = off & 127;
        gload_lds16(abase + (size_t)row * D_MODEL + (colb >> 1), (char*)As + off);
      }
    } else {
      const float* p = asrc + kk * BK;
      #pragma unroll
      for (int i = 0; i < 4; ++i) {
        float4 x0 = *(const float4*)(p + i * 8);
        float4 x1 = *(const float4*)(p + i * 8 + 4);
        *(s16x8*)(adst + i * 8) = cvt8(x0, x1);
      }
    }
    if constexpr (PRE) {
      const u16* bbase = bsrcb + kk * BK;
      #pragma unroll
      for (int i = 0; i < 4; ++i) {
        int off = wv * 4096 + i * 1024 + lane * 16;
        int row = off >> 7, colb = off & 127;
        gload_lds16(bbase + (size_t)row * D_MODEL + (colb >> 1), (char*)Bs + off);
      }
    } else {
      const float* q = bsrcf + (size_t)br * D_MODEL + kk * BK + bc;
      u16* bdst = Bs + br * BK + bc;
      #pragma unroll
      for (int i = 0; i < 4; ++i) {
        float4 x0 = *(const float4*)(q + i * 8);
        float4 x1 = *(const float4*)(q + i * 8 + 4);
        *(s16x8*)(bdst + i * 8) = cvt8(x0, x1);
      }
    }
    __syncthreads();
    #pragma unroll
    for (int kb = 0; kb < 2; ++kb) {
      s16x8 af[4], bf[4];
      #pragma unroll
      for (int m = 0; m < 4; ++m)
        af[m] = *(const s16x8*)(As + (wm * 64 + m * 16 + ll) * BK + kb * 32 + lg * 8);
      #pragma unroll
      for (int n = 0; n < 4; ++n)
        bf[n] = *(const s16x8*)(Bs + (wn * 64 + n * 16 + ll) * BK + kb * 32 + lg * 8);
      #pragma unroll
      for (int m = 0; m < 4; ++m)
        #pragma unroll
        for (int n = 0; n < 4; ++n)
          acc[m][n] = __builtin_amdgcn_mfma_f32_16x16x32_bf16(af[m], bf[n], acc[m][n], 0, 0, 0);
    }
  }

  const int hc0 = fcol0 - f0;
  #pragma unroll
  for (int m = 0; m < 4; ++m) {
    #pragma unroll
    for (int r = 0; r < 4; ++r) {
      int row = wm * 64 + m * 16 + lg * 4 + r;
      u16* hp = H + (size_t)(grow0 + row) * W + hc0 + wn * 64 + ll;
      #pragma unroll
      for (int n = 0; n < 4; ++n) {
        float v = acc[m][n][r];
        hp[n * 16] = f2bf(v > 0.f ? v : 0.f);
      }
    }
  }
}

// ---------------- GEMM2: Y/out += w .* (H @ Wo^T chunk) ----------------
template <bool PRE, bool YB>
__global__ __launch_bounds__(256, 3)
void moe_gemm2(const u16* __restrict__ H,
               const u16* __restrict__ wob, const float* __restrict__ wof,
               const int* __restrict__ tile_e, const int* __restrict__ tokr,
               const float* __restrict__ wr, float* __restrict__ Y,
               float* __restrict__ out, int W, int f0, int first) {
  __shared__ u16 As[BM * BK];
  __shared__ u16 Bs[BM * BK];
  __shared__ int s_tok[BM];
  __shared__ float s_w[BM];

  const int nwg = gridDim.x;
  const int bid = blockIdx.x;
  const int wg = (bid & 7) * (nwg >> 3) + (bid >> 3);
  const int mt = wg % MT_MAX;
  const int dcol0 = (wg / MT_MAX) * 128;

  const int e = tile_e[mt];
  if (e < 0) return;
  const int grow0 = mt * 128;

  const int tid = threadIdx.x;
  const int lane = tid & 63, wv = tid >> 6;
  const int lg = lane >> 4, ll = lane & 15;
  const int wm = wv >> 1, wn = wv & 1;

  if (tid < BM) { s_tok[tid] = tokr[grow0 + tid]; s_w[tid] = wr[grow0 + tid]; }
  __syncthreads();

  const u16* abase = H + (size_t)grow0 * W;
  const u16*   bsrcb = PRE ? wob + ((size_t)e * D_MODEL + dcol0) * D_FF : nullptr;
  const float* bsrcf = PRE ? nullptr : wof + ((size_t)e * D_MODEL + dcol0) * D_FF;
  const int br = tid >> 1, bc = (tid & 1) * 32;

  f32x4 acc[4][4];
  #pragma unroll
  for (int m = 0; m < 4; ++m)
    #pragma unroll
    for (int n = 0; n < 4; ++n) acc[m][n] = (f32x4){0.f, 0.f, 0.f, 0.f};

  for (int kk = 0; kk < W / BK; ++kk) {
    __syncthreads();
    #pragma unroll
    for (int i = 0; i < 4; ++i) {
      int off = wv * 4096 + i * 1024 + lane * 16;
      int row = off >> 7, colb = off & 127;
      gload_lds16(abase + (size_t)row * W + kk * BK + (colb >> 1), (char*)As + off);
    }
    if constexpr (PRE) {
      #pragma unroll
      for (int i = 0; i < 4; ++i) {
        int off = wv * 4096 + i * 1024 + lane * 16;
        int row = off >> 7, colb = off & 127;
        gload_lds16(bsrcb + (size_t)row * D_FF + f0 + kk * BK + (colb >> 1),
                    (char*)Bs + off);
      }
    } else {
      const float* q = bsrcf + (size_t)br * D_FF + f0 + kk * BK + bc;
      u16* bdst = Bs + br * BK + bc;
      #pragma unroll
      for (int i = 0; i < 4; ++i) {
        float4 x0 = *(const float4*)(q + i * 8);
        float4 x1 = *(const float4*)(q + i * 8 + 4);
        *(s16x8*)(bdst + i * 8) = cvt8(x0, x1);
      }
    }
    __syncthreads();
    #pragma unroll
    for (int kb = 0; kb < 2; ++kb) {
      s16x8 af[4], bf[4];
      #pragma unroll
      for (int m = 0; m < 4; ++m)
        af[m] = *(const s16x8*)(As + (wm * 64 + m * 16 + ll) * BK + kb * 32 + lg * 8);
      #pragma unroll
      for (int n = 0; n < 4; ++n)
        bf[n] = *(const s16x8*)(Bs + (wn * 64 + n * 16 + ll) * BK + kb * 32 + lg * 8);
      #pragma unroll
      for (int m = 0; m < 4; ++m)
        #pragma unroll
        for (int n = 0; n < 4; ++n)
          acc[m][n] = __builtin_amdgcn_mfma_f32_16x16x32_bf16(af[m], bf[n], acc[m][n], 0, 0, 0);
    }
  }

  #pragma unroll
  for (int m = 0; m < 4; ++m) {
    #pragma unroll
    for (int r = 0; r < 4; ++r) {
      int row = wm * 64 + m * 16 + lg * 4 + r;
      float w = s_w[row];
      if constexpr (YB) {
        float* yp = Y + (size_t)(grow0 + row) * D_MODEL + dcol0 + wn * 64 + ll;
        #pragma unroll
        for (int n = 0; n < 4; ++n) {
          float v = acc[m][n][r] * w;
          if (first) yp[n * 16] = v; else yp[n * 16] += v;
        }
      } else {
        int tok = s_tok[row];
        if (tok >= 0) {
          float* op = out + (size_t)tok * D_MODEL + dcol0 + wn * 64 + ll;
          #pragma unroll
          for (int n = 0; n < 4; ++n)
            atomicAdd(op + n * 16, acc[m][n][r] * w);
        }
      }
    }
  }
}

// ---------------- combine: out[t] = Y[pos0] + Y[pos1] ----------------
__global__ void moe_combine(const float* __restrict__ Y, const int* __restrict__ pos,
                            float* __restrict__ out) {
  int t = blockIdx.x;
  int c = threadIdx.x * 4;
  int p0 = pos[2 * t], p1 = pos[2 * t + 1];
  float4 v = *(const float4*)(Y + (size_t)p0 * D_MODEL + c);
  if (p1 >= 0) {
    float4 u = *(const float4*)(Y + (size_t)p1 * D_MODEL + c);
    v.x += u.x; v.y += u.y; v.z += u.z; v.w += u.w;
  }
  *(float4*)(out + (size_t)t * D_MODEL + c) = v;
}

// ---------------- host ----------------
extern "C" void kernel_launch(void* const* d_in, const int* in_sizes, int n_in,
                              void* d_out, int out_size, void* d_ws, size_t ws_size,
                              hipStream_t stream) {
  const float* hs  = (const float*)d_in[0];
  const int*   sel = (const int*)d_in[1];
  const float* rw  = (const float*)d_in[2];
  const float* wi  = (const float*)d_in[3];
  const float* wo  = (const float*)d_in[4];
  float* out = (float*)d_out;

  const size_t NW   = (size_t)NE * D_FF * D_MODEL;
  const size_t CTRL = 1u << 20;                               // ~763KB + pads
  const size_t WB   = 2 * NW * sizeof(u16);                   // 128 MiB
  const size_t XGB  = (size_t)ROWS_MAX * D_MODEL * 2;         // 34 MiB
  const size_t YBB  = (size_t)ROWS_MAX * D_MODEL * 4;         // 68 MiB
  const size_t HB   = (size_t)ROWS_MAX * D_FF * 2;            // 136 MiB

  // ---- feature selection ----
  int FS = 32; bool PRE = false, YB = false, XG = false; double bs = -1e18;
  for (int f : {1, 2, 4, 8, 16, 32}) {
    size_t need = CTRL + HB / f;
    if (need > ws_size) continue;
    size_t rem = ws_size - need;
    bool P = rem >= WB;  if (P) rem -= WB;
    bool Y = rem >= YBB; if (Y) rem -= YBB;
    bool X = rem >= XGB; if (X) rem -= XGB;
    double sc = (P ? 150 : 0) + (Y ? 60 : 0) + (X ? 30 : 0) - 25.0 * (f - 1);
    if (sc > bs) { bs = sc; FS = f; PRE = P; YB = Y; XG = X; }
  }

  // ---- ws layout ----
  size_t off = 0;
  auto take = [&](size_t b) -> char* {
    char* r = (char*)d_ws + off; off = (off + b + 255) & ~(size_t)255; return r;
  };
  int*   tidx = (int*)take((size_t)NE * T_TOK * 4);
  float* tw   = (float*)take((size_t)NE * T_TOK * 4);
  int*   tokr = (int*)take((size_t)ROWS_MAX * 4);
  float* wrr  = (float*)take((size_t)ROWS_MAX * 4);
  int*   te   = (int*)take(MT_MAX * 4);
  int*   cnt  = (int*)take(256);
  int*   pos  = (int*)take((size_t)T_TOK * 2 * 4);
  int*   pcnt = (int*)take((size_t)T_TOK * 4);
  off = CTRL;
  u16 *wib = nullptr, *wob = nullptr; u16* Xg = nullptr; float* Ybuf = nullptr;
  if (PRE) { wib = (u16*)take(NW * 2); wob = (u16*)take(NW * 2); }
  if (XG)  { Xg = (u16*)take(XGB); }
  if (YB)  { Ybuf = (float*)take(YBB); }
  u16* Hbuf = (u16*)take(HB / FS);

  // ---- routing ----
  hipMemsetAsync(cnt, 0, 256, stream);
  hipMemsetAsync(pcnt, 0, (size_t)T_TOK * 4, stream);
  hipMemsetAsync(pos, 0xFF, (size_t)T_TOK * 2 * 4, stream);
  if (!YB) hipMemsetAsync(d_out, 0, (size_t)out_size * sizeof(float), stream);
  moe_route<<<T_TOK / 256, 256, 0, stream>>>(sel, rw, cnt, tidx, tw);
  moe_tilemap<<<1, 256, 0, stream>>>(cnt, tidx, tw, te, tokr, wrr, pos, pcnt);
  if (XG)  moe_gather_x<<<ROWS_MAX, 256, 0, stream>>>(hs, tokr, Xg);
  if (PRE) moe_cvt_w<<<(int)(2 * NW / 8 / 256), 256, 0, stream>>>(wi, wo, wib, wob);

  // ---- GEMM passes ----
  const int W = D_FF / FS;
  const int g1 = MT_MAX * (W / 128);
  const int g2 = MT_MAX * (D_MODEL / 128);
  for (int p = 0; p < FS; ++p) {
    const int f0 = p * W;
    const int first = (p == 0);
    if (PRE) {
      if (XG) moe_gemm1<true, true><<<g1, 256, 0, stream>>>(hs, Xg, wib, nullptr, te, tokr, Hbuf, W, f0);
      else    moe_gemm1<true, false><<<g1, 256, 0, stream>>>(hs, nullptr, wib, nullptr, te, tokr, Hbuf, W, f0);
      if (YB) moe_gemm2<true, true><<<g2, 256, 0, stream>>>(Hbuf, wob, nullptr, te, tokr, wrr, Ybuf, out, W, f0, first);
      else    moe_gemm2<true, false><<<g2, 256, 0, stream>>>(Hbuf, wob, nullptr, te, tokr, wrr, nullptr, out, W, f0, first);
    } else {
      if (XG) moe_gemm1<false, true><<<g1, 256, 0, stream>>>(hs, Xg, nullptr, wi, te, tokr, Hbuf, W, f0);
      else    moe_gemm1<false, false><<<g1, 256, 0, stream>>>(hs, nullptr, nullptr, wi, te, tokr, Hbuf, W, f0);
      if (YB) moe_gemm2<false, true><<<g2, 256, 0, stream>>>(Hbuf, nullptr, wo, te, tokr, wrr, Ybuf, out, W, f0, first);
      else    moe_gemm2<false, false><<<g2, 256, 0, stream>>>(Hbuf, nullptr, wo, te, tokr, wrr, nullptr, out, W, f0, first);
    }
  }
  if (YB) moe_combine<<<T_TOK, 256, 0, stream>>>(Ybuf, pos, out);
}